// Round 6
// baseline (73.348 us; speedup 1.0000x reference)
//
#include <hip/hip_runtime.h>
#include <hip/hip_bf16.h>

#define S_DIM 2048
#define B_DIM 32
#define E_DIM 1024
#define H_DIM 1024

// v_enc/v_dec two-stage reduce
#define VCHUNKS 32           // 32 chunks of 32 h-rows each

// k3 decomposition (R3 config, best so far): each wave owns CH s-rows,
// 4 waves/block, 1024 blocks = 4 blocks/CU (grid-limited residency, so
// VGPR tier can float up to ~128 for free).
#define CH 16
#define GROUP 4
#define WPB 4
#define ROWS_PER_BLOCK (CH * WPB)             // 64
#define BLOCKS_PER_B (S_DIM / ROWS_PER_BLOCK) // 32
#define NBLK (B_DIM * BLOCKS_PER_B)           // 1024

// ---------------- workspace layout (floats) ----------------
// penc  [VCHUNKS][E]      32768
// pdec  [VCHUNKS][H]      32768
// venc  [E]               1024
// vdec  [H]               1024
// expw  [B][S]            65536
// pl    [NBLK]            1024
// pctx  [NBLK][E]         1048576
// total ~4.7 MB

__global__ __launch_bounds__(256) void k1_partial_v(
    const float* __restrict__ W_enc, const float* __restrict__ W_dec,
    const float* __restrict__ w_score, float* __restrict__ penc,
    float* __restrict__ pdec) {
  int bid = blockIdx.x;           // 0..255 (128 enc, 128 dec)
  int t = threadIdx.x;
  bool enc = bid < 128;
  int idx = enc ? bid : bid - 128;
  int hc = idx >> 2;              // 0..31 h-chunk
  int e0 = (idx & 3) << 8;        // 0,256,512,768
  const float* M = enc ? W_enc : W_dec;
  int h0 = hc * 32;
  float acc = 0.f;
#pragma unroll 8
  for (int r = 0; r < 32; ++r) {
    float w = w_score[h0 + r];
    acc = fmaf(w, M[(size_t)(h0 + r) * E_DIM + e0 + t], acc);
  }
  float* dst = enc ? penc : pdec;
  dst[hc * E_DIM + e0 + t] = acc;
}

__global__ __launch_bounds__(256) void k2_finalize_v(
    const float* __restrict__ penc, const float* __restrict__ pdec,
    float* __restrict__ venc, float* __restrict__ vdec) {
  int g = blockIdx.x * 256 + threadIdx.x;  // 0..2047
  bool enc = g < E_DIM;
  const float* p = enc ? penc : pdec;
  int e = enc ? g : g - E_DIM;
  float acc = 0.f;
#pragma unroll 8
  for (int c = 0; c < VCHUNKS; ++c) acc += p[c * E_DIM + e];
  (enc ? venc : vdec)[e] = acc;
}

__device__ __forceinline__ float wave_allreduce_sum(float v) {
#pragma unroll
  for (int off = 1; off < 64; off <<= 1) v += __shfl_xor(v, off, 64);
  return v;
}

__device__ __forceinline__ float fast_tanh(float x) {
  // tanh(x) = 1 - 2/(e^{2x}+1); exact saturation as e^{2x} -> 0 or inf
  float e2 = __expf(2.f * x);
  return 1.f - 2.f * __builtin_amdgcn_rcpf(e2 + 1.f);
}

// Hide a pointer's provenance so the compiler cannot CSE the phase-B
// reloads with phase-A loads (which would keep 4 full row-sets live
// in VGPRs -> the R2 spill). Reloads hit L1/L2/L3, not HBM.
__device__ __forceinline__ const float* launder(const float* p) {
  uintptr_t v = (uintptr_t)p;
  asm volatile("" : "+v"(v));
  return (const float*)v;
}

// Main streaming pass: scores + exp + fused partial weighted-context.
// Two-phase per 4-row group: (A) 4 back-to-back dot products (row regs
// die at the dot-FMA -> 16KB of loads pipeline per wave), 4 interleaved
// shuffle-reduce chains, float4 expw store; (B) re-read the 4 rows from
// cache (laundered) and accumulate ctx.
__global__ __launch_bounds__(256) void k3_stream(
    const float* __restrict__ h_enc, const float* __restrict__ h_t,
    const float* __restrict__ venc, const float* __restrict__ vdec,
    float* __restrict__ expw, float* __restrict__ pl,
    float* __restrict__ pctx) {
  int bid = blockIdx.x;
  int t = threadIdx.x;
  int w = t >> 6;
  int lane = t & 63;
  int b = bid >> 5;                 // 32 blocks per b
  int cbi = bid & 31;
  int s0 = cbi * ROWS_PER_BLOCK + w * CH;
  int e_base = lane * 4;            // lane covers e = lane*4 + k*256, k=0..3

  __shared__ float lctx[WPB][E_DIM];   // 16 KB
  __shared__ float ll[WPB];

  float4 ve[4];
#pragma unroll
  for (int k = 0; k < 4; ++k)
    ve[k] = *reinterpret_cast<const float4*>(venc + e_base + k * 256);

  // c_b = vdec . h_t[b]
  float cb = 0.f;
#pragma unroll
  for (int k = 0; k < 4; ++k) {
    float4 vd = *reinterpret_cast<const float4*>(vdec + e_base + k * 256);
    float4 ht = *reinterpret_cast<const float4*>(h_t + b * H_DIM + e_base + k * 256);
    cb = fmaf(vd.x, ht.x, cb);
    cb = fmaf(vd.y, ht.y, cb);
    cb = fmaf(vd.z, ht.z, cb);
    cb = fmaf(vd.w, ht.w, cb);
  }
  cb = wave_allreduce_sum(cb);

  float4 ctx[4];
#pragma unroll
  for (int k = 0; k < 4; ++k) ctx[k] = make_float4(0.f, 0.f, 0.f, 0.f);
  float lsum = 0.f;

  const size_t row_stride = (size_t)B_DIM * E_DIM;  // 32768 floats
  const float* base0 = h_enc + ((size_t)s0 * B_DIM + b) * E_DIM + e_base;

  for (int g = 0; g < CH / GROUP; ++g) {
    const float* gbase = base0 + (size_t)g * GROUP * row_stride;

    // ---- phase A: 4 dot products, rows' registers die at the FMA ----
    float d0, d1, d2, d3;
#pragma unroll
    for (int r = 0; r < GROUP; ++r) {
      const float* row = gbase + (size_t)r * row_stride;
      float4 a0 = *reinterpret_cast<const float4*>(row);
      float4 a1 = *reinterpret_cast<const float4*>(row + 256);
      float4 a2 = *reinterpret_cast<const float4*>(row + 512);
      float4 a3 = *reinterpret_cast<const float4*>(row + 768);
      float d = 0.f;
      d = fmaf(a0.x, ve[0].x, d); d = fmaf(a0.y, ve[0].y, d);
      d = fmaf(a0.z, ve[0].z, d); d = fmaf(a0.w, ve[0].w, d);
      d = fmaf(a1.x, ve[1].x, d); d = fmaf(a1.y, ve[1].y, d);
      d = fmaf(a1.z, ve[1].z, d); d = fmaf(a1.w, ve[1].w, d);
      d = fmaf(a2.x, ve[2].x, d); d = fmaf(a2.y, ve[2].y, d);
      d = fmaf(a2.z, ve[2].z, d); d = fmaf(a2.w, ve[2].w, d);
      d = fmaf(a3.x, ve[3].x, d); d = fmaf(a3.y, ve[3].y, d);
      d = fmaf(a3.z, ve[3].z, d); d = fmaf(a3.w, ve[3].w, d);
      if (r == 0) d0 = d; else if (r == 1) d1 = d;
      else if (r == 2) d2 = d; else d3 = d;
    }

    // 4 interleaved butterfly chains (ILP across independent reductions)
#pragma unroll
    for (int off = 1; off < 64; off <<= 1) {
      d0 += __shfl_xor(d0, off, 64);
      d1 += __shfl_xor(d1, off, 64);
      d2 += __shfl_xor(d2, off, 64);
      d3 += __shfl_xor(d3, off, 64);
    }

    float w0 = __expf(fast_tanh(d0 + cb));
    float w1 = __expf(fast_tanh(d1 + cb));
    float w2 = __expf(fast_tanh(d2 + cb));
    float w3 = __expf(fast_tanh(d3 + cb));
    if (lane == 0)
      *reinterpret_cast<float4*>(expw + b * S_DIM + s0 + g * GROUP) =
          make_float4(w0, w1, w2, w3);
    lsum += (w0 + w1) + (w2 + w3);

    // ---- phase B: cache-hot re-read, accumulate ctx ----
#pragma unroll
    for (int r = 0; r < GROUP; ++r) {
      const float* row = launder(gbase + (size_t)r * row_stride);
      float wr = (r == 0) ? w0 : (r == 1) ? w1 : (r == 2) ? w2 : w3;
      float4 a0 = *reinterpret_cast<const float4*>(row);
      float4 a1 = *reinterpret_cast<const float4*>(row + 256);
      float4 a2 = *reinterpret_cast<const float4*>(row + 512);
      float4 a3 = *reinterpret_cast<const float4*>(row + 768);
      ctx[0].x = fmaf(wr, a0.x, ctx[0].x); ctx[0].y = fmaf(wr, a0.y, ctx[0].y);
      ctx[0].z = fmaf(wr, a0.z, ctx[0].z); ctx[0].w = fmaf(wr, a0.w, ctx[0].w);
      ctx[1].x = fmaf(wr, a1.x, ctx[1].x); ctx[1].y = fmaf(wr, a1.y, ctx[1].y);
      ctx[1].z = fmaf(wr, a1.z, ctx[1].z); ctx[1].w = fmaf(wr, a1.w, ctx[1].w);
      ctx[2].x = fmaf(wr, a2.x, ctx[2].x); ctx[2].y = fmaf(wr, a2.y, ctx[2].y);
      ctx[2].z = fmaf(wr, a2.z, ctx[2].z); ctx[2].w = fmaf(wr, a2.w, ctx[2].w);
      ctx[3].x = fmaf(wr, a3.x, ctx[3].x); ctx[3].y = fmaf(wr, a3.y, ctx[3].y);
      ctx[3].z = fmaf(wr, a3.z, ctx[3].z); ctx[3].w = fmaf(wr, a3.w, ctx[3].w);
    }
  }

  // block-level reduction of the 4 waves' partials
#pragma unroll
  for (int k = 0; k < 4; ++k)
    *reinterpret_cast<float4*>(&lctx[w][e_base + k * 256]) = ctx[k];
  if (lane == 0) ll[w] = lsum;
  __syncthreads();

  {
    int e = t * 4;  // each thread reduces 4 consecutive e over the 4 waves
    float4 v0 = *reinterpret_cast<const float4*>(&lctx[0][e]);
    float4 v1 = *reinterpret_cast<const float4*>(&lctx[1][e]);
    float4 v2 = *reinterpret_cast<const float4*>(&lctx[2][e]);
    float4 v3 = *reinterpret_cast<const float4*>(&lctx[3][e]);
    float4 r;
    r.x = (v0.x + v1.x) + (v2.x + v3.x);
    r.y = (v0.y + v1.y) + (v2.y + v3.y);
    r.z = (v0.z + v1.z) + (v2.z + v3.z);
    r.w = (v0.w + v1.w) + (v2.w + v3.w);
    *reinterpret_cast<float4*>(pctx + (size_t)bid * E_DIM + e) = r;
    if (t == 0) pl[bid] = (ll[0] + ll[1]) + (ll[2] + ll[3]);
  }
}

// Final reduce: context = sum(pctx)/l_b ; alphas = expw/l_b
__global__ __launch_bounds__(256) void k4_finalize(
    const float* __restrict__ pl, const float* __restrict__ pctx,
    const float* __restrict__ expw, float* __restrict__ out) {
  int bid = blockIdx.x;  // 0..511 : [0,256) ctx, [256,512) alphas
  int t = threadIdx.x;
  int lane = t & 63;
  bool isCtx = bid < 256;
  int idx = isCtx ? bid : bid - 256;
  int b = idx >> 3;

  __shared__ float s_l;
  __shared__ float s_half[128];

  if (t < 64) {
    float v = (lane < BLOCKS_PER_B) ? pl[b * BLOCKS_PER_B + lane] : 0.f;
    v = wave_allreduce_sum(v);
    if (lane == 0) s_l = v;
  }
  __syncthreads();
  float lb = s_l;

  if (isCtx) {
    int e0 = (idx & 7) * 128;
    int eo = t & 127;
    int c0 = (t >> 7) * 16;  // two halves of the 32 chunks
    const float* base = pctx + (size_t)(b * BLOCKS_PER_B + c0) * E_DIM + e0 + eo;
    float acc = 0.f;
#pragma unroll 8
    for (int c = 0; c < 16; ++c) acc += base[(size_t)c * E_DIM];
    if (t >= 128) s_half[eo] = acc;
    __syncthreads();
    if (t < 128) out[b * E_DIM + e0 + eo] = (acc + s_half[eo]) / lb;
  } else {
    int sb = (idx & 7) * 256;
    int o = b * S_DIM + sb + t;
    out[B_DIM * E_DIM + o] = expw[o] / lb;
  }
}

extern "C" void kernel_launch(void* const* d_in, const int* in_sizes, int n_in,
                              void* d_out, int out_size, void* d_ws, size_t ws_size,
                              hipStream_t stream) {
  const float* h_t     = (const float*)d_in[0];
  const float* h_enc   = (const float*)d_in[1];
  const float* W_enc   = (const float*)d_in[2];
  const float* W_dec   = (const float*)d_in[3];
  const float* w_score = (const float*)d_in[4];
  float* out = (float*)d_out;
  float* ws = (float*)d_ws;

  float* penc = ws;                  // 32768
  float* pdec = penc + 32768;        // 32768
  float* venc = pdec + 32768;        // 1024
  float* vdec = venc + 1024;         // 1024
  float* expw = vdec + 1024;         // 65536
  float* pl   = expw + 65536;        // 1024
  float* pctx = pl + 1024;           // 1048576

  hipLaunchKernelGGL(k1_partial_v, dim3(256), dim3(256), 0, stream,
                     W_enc, W_dec, w_score, penc, pdec);
  hipLaunchKernelGGL(k2_finalize_v, dim3(8), dim3(256), 0, stream,
                     penc, pdec, venc, vdec);
  hipLaunchKernelGGL(k3_stream, dim3(NBLK), dim3(256), 0, stream,
                     h_enc, h_t, venc, vdec, expw, pl, pctx);
  hipLaunchKernelGGL(k4_finalize, dim3(512), dim3(256), 0, stream,
                     pl, pctx, expw, out);
}

// Round 7
// 55.688 us; speedup vs baseline: 1.3171x; 1.3171x over previous
//
#include <hip/hip_runtime.h>
#include <hip/hip_bf16.h>

#define S_DIM 2048
#define B_DIM 32
#define E_DIM 1024
#define H_DIM 1024

// v_enc/v_dec two-stage reduce
#define VCHUNKS 32           // 32 chunks of 32 h-rows each

// k3 decomposition (R3 config, best so far): each wave owns CH s-rows,
// 4 waves/block, 1024 blocks = 4 blocks/CU. Grid-limited residency ->
// the 128-VGPR tier costs nothing; amdgpu_waves_per_eu(4) grants it.
#define CH 16
#define WPB 4
#define ROWS_PER_BLOCK (CH * WPB)             // 64
#define BLOCKS_PER_B (S_DIM / ROWS_PER_BLOCK) // 32
#define NBLK (B_DIM * BLOCKS_PER_B)           // 1024

// ---------------- workspace layout (floats) ----------------
// penc  [VCHUNKS][E]      32768
// pdec  [VCHUNKS][H]      32768
// venc  [E]               1024
// vdec  [H]               1024
// expw  [B][S]            65536
// pl    [NBLK]            1024
// pctx  [NBLK][E]         1048576
// total ~4.7 MB

__global__ __launch_bounds__(256) void k1_partial_v(
    const float* __restrict__ W_enc, const float* __restrict__ W_dec,
    const float* __restrict__ w_score, float* __restrict__ penc,
    float* __restrict__ pdec) {
  int bid = blockIdx.x;           // 0..255 (128 enc, 128 dec)
  int t = threadIdx.x;
  bool enc = bid < 128;
  int idx = enc ? bid : bid - 128;
  int hc = idx >> 2;              // 0..31 h-chunk
  int e0 = (idx & 3) << 8;        // 0,256,512,768
  const float* M = enc ? W_enc : W_dec;
  int h0 = hc * 32;
  float acc = 0.f;
#pragma unroll 8
  for (int r = 0; r < 32; ++r) {
    float w = w_score[h0 + r];
    acc = fmaf(w, M[(size_t)(h0 + r) * E_DIM + e0 + t], acc);
  }
  float* dst = enc ? penc : pdec;
  dst[hc * E_DIM + e0 + t] = acc;
}

__global__ __launch_bounds__(256) void k2_finalize_v(
    const float* __restrict__ penc, const float* __restrict__ pdec,
    float* __restrict__ venc, float* __restrict__ vdec) {
  int g = blockIdx.x * 256 + threadIdx.x;  // 0..2047
  bool enc = g < E_DIM;
  const float* p = enc ? penc : pdec;
  int e = enc ? g : g - E_DIM;
  float acc = 0.f;
#pragma unroll 8
  for (int c = 0; c < VCHUNKS; ++c) acc += p[c * E_DIM + e];
  (enc ? venc : vdec)[e] = acc;
}

__device__ __forceinline__ float wave_allreduce_sum(float v) {
#pragma unroll
  for (int off = 1; off < 64; off <<= 1) v += __shfl_xor(v, off, 64);
  return v;
}

__device__ __forceinline__ float fast_tanh(float x) {
  // tanh(x) = 1 - 2/(e^{2x}+1); exact saturation as e^{2x} -> 0 or inf
  float e2 = __expf(2.f * x);
  return 1.f - 2.f * __builtin_amdgcn_rcpf(e2 + 1.f);
}

// Main streaming pass: scores + exp + fused partial weighted-context.
// Distance-1 software pipeline: row i+1's loads are issued at the top of
// each iteration, row i is consumed entirely from registers (no re-fetch
// -- the R6 phase-B reload went past L1 and cost +17us). Rolled loop
// (#pragma unroll 1) keeps live state to 2 row-sets.
__global__ __attribute__((amdgpu_waves_per_eu(4)))
__launch_bounds__(256) void k3_stream(
    const float* __restrict__ h_enc, const float* __restrict__ h_t,
    const float* __restrict__ venc, const float* __restrict__ vdec,
    float* __restrict__ expw, float* __restrict__ pl,
    float* __restrict__ pctx) {
  int bid = blockIdx.x;
  int t = threadIdx.x;
  int w = t >> 6;
  int lane = t & 63;
  int b = bid >> 5;                 // 32 blocks per b
  int cbi = bid & 31;
  int s0 = cbi * ROWS_PER_BLOCK + w * CH;
  int e_base = lane * 4;            // lane covers e = lane*4 + k*256, k=0..3

  __shared__ float lctx[WPB][E_DIM];   // 16 KB
  __shared__ float ll[WPB];

  float4 ve[4];
#pragma unroll
  for (int k = 0; k < 4; ++k)
    ve[k] = *reinterpret_cast<const float4*>(venc + e_base + k * 256);

  // c_b = vdec . h_t[b]
  float cb = 0.f;
#pragma unroll
  for (int k = 0; k < 4; ++k) {
    float4 vd = *reinterpret_cast<const float4*>(vdec + e_base + k * 256);
    float4 ht = *reinterpret_cast<const float4*>(h_t + b * H_DIM + e_base + k * 256);
    cb = fmaf(vd.x, ht.x, cb);
    cb = fmaf(vd.y, ht.y, cb);
    cb = fmaf(vd.z, ht.z, cb);
    cb = fmaf(vd.w, ht.w, cb);
  }
  cb = wave_allreduce_sum(cb);

  float4 ctx[4];
#pragma unroll
  for (int k = 0; k < 4; ++k) ctx[k] = make_float4(0.f, 0.f, 0.f, 0.f);
  float lsum = 0.f;

  const size_t row_stride = (size_t)B_DIM * E_DIM;  // 32768 floats
  const float* base0 = h_enc + ((size_t)s0 * B_DIM + b) * E_DIM + e_base;

  // per-row compute, consuming a row held in registers
  auto body = [&](float4 a0, float4 a1, float4 a2, float4 a3, int s) {
    float d = 0.f;
    d = fmaf(a0.x, ve[0].x, d); d = fmaf(a0.y, ve[0].y, d);
    d = fmaf(a0.z, ve[0].z, d); d = fmaf(a0.w, ve[0].w, d);
    d = fmaf(a1.x, ve[1].x, d); d = fmaf(a1.y, ve[1].y, d);
    d = fmaf(a1.z, ve[1].z, d); d = fmaf(a1.w, ve[1].w, d);
    d = fmaf(a2.x, ve[2].x, d); d = fmaf(a2.y, ve[2].y, d);
    d = fmaf(a2.z, ve[2].z, d); d = fmaf(a2.w, ve[2].w, d);
    d = fmaf(a3.x, ve[3].x, d); d = fmaf(a3.y, ve[3].y, d);
    d = fmaf(a3.z, ve[3].z, d); d = fmaf(a3.w, ve[3].w, d);
    d = wave_allreduce_sum(d);
    float wgt = __expf(fast_tanh(d + cb));
    if (lane == 0) expw[b * S_DIM + s] = wgt;
    lsum += wgt;
    ctx[0].x = fmaf(wgt, a0.x, ctx[0].x); ctx[0].y = fmaf(wgt, a0.y, ctx[0].y);
    ctx[0].z = fmaf(wgt, a0.z, ctx[0].z); ctx[0].w = fmaf(wgt, a0.w, ctx[0].w);
    ctx[1].x = fmaf(wgt, a1.x, ctx[1].x); ctx[1].y = fmaf(wgt, a1.y, ctx[1].y);
    ctx[1].z = fmaf(wgt, a1.z, ctx[1].z); ctx[1].w = fmaf(wgt, a1.w, ctx[1].w);
    ctx[2].x = fmaf(wgt, a2.x, ctx[2].x); ctx[2].y = fmaf(wgt, a2.y, ctx[2].y);
    ctx[2].z = fmaf(wgt, a2.z, ctx[2].z); ctx[2].w = fmaf(wgt, a2.w, ctx[2].w);
    ctx[3].x = fmaf(wgt, a3.x, ctx[3].x); ctx[3].y = fmaf(wgt, a3.y, ctx[3].y);
    ctx[3].z = fmaf(wgt, a3.z, ctx[3].z); ctx[3].w = fmaf(wgt, a3.w, ctx[3].w);
  };

  // prologue: load row s0
  float4 c0 = *reinterpret_cast<const float4*>(base0);
  float4 c1 = *reinterpret_cast<const float4*>(base0 + 256);
  float4 c2 = *reinterpret_cast<const float4*>(base0 + 512);
  float4 c3 = *reinterpret_cast<const float4*>(base0 + 768);

#pragma unroll 1
  for (int i = 1; i < CH; ++i) {
    const float* nrow = base0 + (size_t)i * row_stride;
    float4 n0 = *reinterpret_cast<const float4*>(nrow);
    float4 n1 = *reinterpret_cast<const float4*>(nrow + 256);
    float4 n2 = *reinterpret_cast<const float4*>(nrow + 512);
    float4 n3 = *reinterpret_cast<const float4*>(nrow + 768);
    body(c0, c1, c2, c3, s0 + i - 1);
    c0 = n0; c1 = n1; c2 = n2; c3 = n3;
  }
  body(c0, c1, c2, c3, s0 + CH - 1);

  // block-level reduction of the 4 waves' partials
#pragma unroll
  for (int k = 0; k < 4; ++k)
    *reinterpret_cast<float4*>(&lctx[w][e_base + k * 256]) = ctx[k];
  if (lane == 0) ll[w] = lsum;
  __syncthreads();

  {
    int e = t * 4;  // each thread reduces 4 consecutive e over the 4 waves
    float4 v0 = *reinterpret_cast<const float4*>(&lctx[0][e]);
    float4 v1 = *reinterpret_cast<const float4*>(&lctx[1][e]);
    float4 v2 = *reinterpret_cast<const float4*>(&lctx[2][e]);
    float4 v3 = *reinterpret_cast<const float4*>(&lctx[3][e]);
    float4 r;
    r.x = (v0.x + v1.x) + (v2.x + v3.x);
    r.y = (v0.y + v1.y) + (v2.y + v3.y);
    r.z = (v0.z + v1.z) + (v2.z + v3.z);
    r.w = (v0.w + v1.w) + (v2.w + v3.w);
    *reinterpret_cast<float4*>(pctx + (size_t)bid * E_DIM + e) = r;
    if (t == 0) pl[bid] = (ll[0] + ll[1]) + (ll[2] + ll[3]);
  }
}

// Final reduce: context = sum(pctx)/l_b ; alphas = expw/l_b
__global__ __launch_bounds__(256) void k4_finalize(
    const float* __restrict__ pl, const float* __restrict__ pctx,
    const float* __restrict__ expw, float* __restrict__ out) {
  int bid = blockIdx.x;  // 0..511 : [0,256) ctx, [256,512) alphas
  int t = threadIdx.x;
  int lane = t & 63;
  bool isCtx = bid < 256;
  int idx = isCtx ? bid : bid - 256;
  int b = idx >> 3;

  __shared__ float s_l;
  __shared__ float s_half[128];

  if (t < 64) {
    float v = (lane < BLOCKS_PER_B) ? pl[b * BLOCKS_PER_B + lane] : 0.f;
    v = wave_allreduce_sum(v);
    if (lane == 0) s_l = v;
  }
  __syncthreads();
  float lb = s_l;

  if (isCtx) {
    int e0 = (idx & 7) * 128;
    int eo = t & 127;
    int c0 = (t >> 7) * 16;  // two halves of the 32 chunks
    const float* base = pctx + (size_t)(b * BLOCKS_PER_B + c0) * E_DIM + e0 + eo;
    float acc = 0.f;
#pragma unroll 8
    for (int c = 0; c < 16; ++c) acc += base[(size_t)c * E_DIM];
    if (t >= 128) s_half[eo] = acc;
    __syncthreads();
    if (t < 128) out[b * E_DIM + e0 + eo] = (acc + s_half[eo]) / lb;
  } else {
    int sb = (idx & 7) * 256;
    int o = b * S_DIM + sb + t;
    out[B_DIM * E_DIM + o] = expw[o] / lb;
  }
}

extern "C" void kernel_launch(void* const* d_in, const int* in_sizes, int n_in,
                              void* d_out, int out_size, void* d_ws, size_t ws_size,
                              hipStream_t stream) {
  const float* h_t     = (const float*)d_in[0];
  const float* h_enc   = (const float*)d_in[1];
  const float* W_enc   = (const float*)d_in[2];
  const float* W_dec   = (const float*)d_in[3];
  const float* w_score = (const float*)d_in[4];
  float* out = (float*)d_out;
  float* ws = (float*)d_ws;

  float* penc = ws;                  // 32768
  float* pdec = penc + 32768;        // 32768
  float* venc = pdec + 32768;        // 1024
  float* vdec = venc + 1024;         // 1024
  float* expw = vdec + 1024;         // 65536
  float* pl   = expw + 65536;        // 1024
  float* pctx = pl + 1024;           // 1048576

  hipLaunchKernelGGL(k1_partial_v, dim3(256), dim3(256), 0, stream,
                     W_enc, W_dec, w_score, penc, pdec);
  hipLaunchKernelGGL(k2_finalize_v, dim3(8), dim3(256), 0, stream,
                     penc, pdec, venc, vdec);
  hipLaunchKernelGGL(k3_stream, dim3(NBLK), dim3(256), 0, stream,
                     h_enc, h_t, venc, vdec, expw, pl, pctx);
  hipLaunchKernelGGL(k4_finalize, dim3(512), dim3(256), 0, stream,
                     pl, pctx, expw, out);
}